// Round 5
// baseline (261.974 us; speedup 1.0000x reference)
//
#include <hip/hip_runtime.h>

// LocalSorterModel, collapsed + bf16 MFMA (16x16x32), coalesced staging:
//   out[b,r] = sum_x E[b,x] * W[x,r] + const[r],  x = n*1024+d, K=5120
//   WTt[r][x] bf16 built by fold GEMM from Afold[d][k2] (pw_w repack) and
//   C2R[n*128+r][k2] (cls_w pair-fold).  All operands K-contiguous bf16;
//   staging: lanes-along-K global loads -> XOR-swizzled [row][64] LDS tiles.

#define NR 120
#define KXX 5120
#define PM_SLICE (2048*128)

typedef __attribute__((ext_vector_type(8))) short bf8;
typedef __attribute__((ext_vector_type(4))) float f4;

__device__ __forceinline__ unsigned int f2bf(float f) {
    unsigned int x = __builtin_bit_cast(unsigned int, f);
    return (x + 0x7fffu + ((x >> 16) & 1u)) >> 16;
}
__device__ __forceinline__ float bf2f(unsigned short u) {
    unsigned int x = ((unsigned int)u) << 16;
    return __builtin_bit_cast(float, x);
}

// ---- C2R: [640 col][2048 k2] bf16, col = n*128+r (r>=120 zero) ----
__global__ __launch_bounds__(256) void k_prep(const float* __restrict__ cls_w,
                                              unsigned short* __restrict__ C2R) {
    const int col = blockIdx.x, half = blockIdx.y, t = threadIdx.x;
    const int n = col >> 7, r = col & 127;
    unsigned short* dst = C2R + (size_t)col * 2048 + half * 1024 + t * 4;
    if (r >= NR) { *(unsigned long long*)dst = 0ull; return; }
    const float* base = cls_w + (size_t)r * 20480 + t * 4;
    float sx = 0, sy = 0, sz = 0, sw = 0;
    if (half == 0) {
        #pragma unroll
        for (int q = 0; q < 4; q++) {
            float4 v = *(const float4*)(base + (4 * n + q) * 1024);
            sx += v.x; sy += v.y; sz += v.z; sw += v.w;
        }
    } else {
        #pragma unroll
        for (int i = 0; i < 5; i++) {
            if (i == n) continue;
            int q = (n > i) ? (n - 1) : n;
            float4 v = *(const float4*)(base + (4 * i + q) * 1024);
            sx += v.x; sy += v.y; sz += v.z; sw += v.w;
        }
    }
    unsigned long long pk = (unsigned long long)f2bf(sx)
                          | ((unsigned long long)f2bf(sy) << 16)
                          | ((unsigned long long)f2bf(sz) << 32)
                          | ((unsigned long long)f2bf(sw) << 48);
    *(unsigned long long*)dst = pk;
}

// ---- Afold: [1024 d][2048 k2] bf16 = transposed/interleaved pw_w ----
__global__ __launch_bounds__(256) void k_wprep(const float* __restrict__ pw_w,
                                               unsigned short* __restrict__ Afold) {
    __shared__ float T[64][65];
    const int d0 = blockIdx.x * 64, kt0 = blockIdx.y * 64;
    const int h = blockIdx.y >> 4, kr0 = (blockIdx.y & 15) * 64;
    const int t = threadIdx.x;
    #pragma unroll
    for (int lp = 0; lp < 4; lp++) {
        int lk = lp * 16 + (t >> 4);
        float4 v = *(const float4*)(pw_w + (size_t)(kr0 + lk) * 2048 + h * 1024 + d0 + (t & 15) * 4);
        T[lk][(t & 15) * 4 + 0] = v.x; T[lk][(t & 15) * 4 + 1] = v.y;
        T[lk][(t & 15) * 4 + 2] = v.z; T[lk][(t & 15) * 4 + 3] = v.w;
    }
    __syncthreads();
    #pragma unroll
    for (int wp = 0; wp < 2; wp++) {
        int ld = wp * 32 + (t >> 3);
        int lk2 = (t & 7) * 8;
        uint4 o;
        o.x = f2bf(T[lk2 + 0][ld]) | (f2bf(T[lk2 + 1][ld]) << 16);
        o.y = f2bf(T[lk2 + 2][ld]) | (f2bf(T[lk2 + 3][ld]) << 16);
        o.z = f2bf(T[lk2 + 4][ld]) | (f2bf(T[lk2 + 5][ld]) << 16);
        o.w = f2bf(T[lk2 + 6][ld]) | (f2bf(T[lk2 + 7][ld]) << 16);
        *(uint4*)(Afold + (size_t)(d0 + ld) * 2048 + kt0 + lk2) = o;
    }
}

__global__ __launch_bounds__(256) void k_const(const unsigned short* __restrict__ C2R,
                                               const float* __restrict__ pw_b,
                                               const float* __restrict__ cls_b,
                                               float* __restrict__ constv) {
    const int r = blockIdx.x, t = threadIdx.x;
    float acc = 0.f;
    for (int k = t; k < 1024; k += 256) {
        float s = 0.f;
        #pragma unroll
        for (int n = 0; n < 5; n++) s += bf2f(C2R[(size_t)(n * 128 + r) * 2048 + k]);
        acc += s * pw_b[k];
    }
    __shared__ float red[256];
    red[t] = acc; __syncthreads();
    for (int s2 = 128; s2 > 0; s2 >>= 1) {
        if (t < s2) red[t] += red[t + s2];
        __syncthreads();
    }
    if (t == 0) constv[r] = cls_b[r] + red[0];
}

// ---- fold GEMM (MFMA): grid(8,5), full K=2048, emits WTt[128 r][5120] bf16 ----
__global__ __launch_bounds__(256) void k_fold(const unsigned short* __restrict__ Afold,
                                              const unsigned short* __restrict__ C2R,
                                              unsigned short* __restrict__ WTt) {
    __shared__ __align__(16) unsigned short lds[2 * 128 * 64];
    unsigned short* Al = lds;
    unsigned short* Bl = lds + 128 * 64;
    const int d0 = blockIdx.x * 128, n = blockIdx.y;
    const int t = threadIdx.x, lane = t & 63, wv = t >> 6;
    const int wm = wv >> 1, wn = wv & 1;
    const int rr = t >> 3;        // 0..31 row base (per pass p: row = p*32+rr)
    const int f  = t & 7;         // 16B k-slot within row

    f4 acc[4][4];
    #pragma unroll
    for (int i = 0; i < 4; i++)
        #pragma unroll
        for (int j = 0; j < 4; j++) acc[i][j] = (f4){0.f, 0.f, 0.f, 0.f};

    const unsigned short* Ag = Afold + (size_t)d0 * 2048;
    const unsigned short* Bg = C2R + (size_t)(n * 128) * 2048;
    uint4 ra[4], rb[4];
    #pragma unroll
    for (int p = 0; p < 4; p++) {
        ra[p] = *(const uint4*)(Ag + (size_t)(p * 32 + rr) * 2048 + f * 8);
        rb[p] = *(const uint4*)(Bg + (size_t)(p * 32 + rr) * 2048 + f * 8);
    }
    for (int kt = 0; kt < 32; kt++) {
        if (kt) __syncthreads();
        #pragma unroll
        for (int p = 0; p < 4; p++) {
            int row = p * 32 + rr;
            int slot = f ^ (row & 7);
            *(uint4*)(Al + row * 64 + slot * 8) = ra[p];
            *(uint4*)(Bl + row * 64 + slot * 8) = rb[p];
        }
        __syncthreads();
        if (kt + 1 < 32) {
            int kb = (kt + 1) * 64;
            #pragma unroll
            for (int p = 0; p < 4; p++) {
                ra[p] = *(const uint4*)(Ag + (size_t)(p * 32 + rr) * 2048 + kb + f * 8);
                rb[p] = *(const uint4*)(Bg + (size_t)(p * 32 + rr) * 2048 + kb + f * 8);
            }
        }
        #pragma unroll
        for (int s = 0; s < 2; s++) {
            bf8 af[4], bq[4];
            #pragma unroll
            for (int ff = 0; ff < 4; ff++) {
                int rowa = wm * 64 + ff * 16 + (lane & 15);
                int sla = (s * 4 + (lane >> 4)) ^ (rowa & 7);
                af[ff] = *reinterpret_cast<const bf8*>(Al + rowa * 64 + sla * 8);
                int rowb = wn * 64 + ff * 16 + (lane & 15);
                int slb = (s * 4 + (lane >> 4)) ^ (rowb & 7);
                bq[ff] = *reinterpret_cast<const bf8*>(Bl + rowb * 64 + slb * 8);
            }
            #pragma unroll
            for (int i = 0; i < 4; i++)
                #pragma unroll
                for (int j = 0; j < 4; j++)
                    acc[i][j] = __builtin_amdgcn_mfma_f32_16x16x32_bf16(af[i], bq[j], acc[i][j], 0, 0, 0);
        }
    }
    // repack D (rows=d, cols=r) -> LDS T[128 r][128 d] bf16, coalesced WTt store
    __syncthreads();
    unsigned short* T = lds;
    #pragma unroll
    for (int i = 0; i < 4; i++) {
        int dbase = wm * 64 + i * 16 + (lane >> 4) * 4;
        #pragma unroll
        for (int j = 0; j < 4; j++) {
            int cl = wn * 64 + j * 16 + (lane & 15);
            unsigned long long pk = (unsigned long long)f2bf(acc[i][j][0])
                                  | ((unsigned long long)f2bf(acc[i][j][1]) << 16)
                                  | ((unsigned long long)f2bf(acc[i][j][2]) << 32)
                                  | ((unsigned long long)f2bf(acc[i][j][3]) << 48);
            *(unsigned long long*)(T + cl * 128 + dbase) = pk;
        }
    }
    __syncthreads();
    #pragma unroll
    for (int rep = 0; rep < 4; rep++) {
        int c = rep * 32 + (t >> 3);
        int db = (t & 7) * 16;
        uint4 v0 = *(const uint4*)(T + c * 128 + db);
        uint4 v1 = *(const uint4*)(T + c * 128 + db + 8);
        unsigned short* w = WTt + (size_t)c * KXX + n * 1024 + d0 + db;
        *(uint4*)w = v0;
        *(uint4*)(w + 8) = v1;
    }
}

// ---- main GEMM (MFMA): A=E fp32 (cvt in staging), B=WTt bf16; fp32 partials ----
__global__ __launch_bounds__(256) void k_main(const float* __restrict__ E,
                                              const unsigned short* __restrict__ WTt,
                                              float* __restrict__ Pm, int kchunk) {
    __shared__ __align__(16) unsigned short lds[2 * 128 * 64];
    unsigned short* Al = lds;
    unsigned short* Bl = lds + 128 * 64;
    const int m0 = blockIdx.x * 128;
    const int kc0 = blockIdx.y * kchunk;
    const int t = threadIdx.x, lane = t & 63, wv = t >> 6;
    const int wm = wv >> 1, wn = wv & 1;
    const int rr = t >> 3;
    const int f  = t & 7;

    f4 acc[4][4];
    #pragma unroll
    for (int i = 0; i < 4; i++)
        #pragma unroll
        for (int j = 0; j < 4; j++) acc[i][j] = (f4){0.f, 0.f, 0.f, 0.f};

    const float* Ag = E + (size_t)m0 * KXX + kc0;
    const unsigned short* Bg = WTt + kc0;
    float4 ra[4][2];
    uint4 rb[4];
    #pragma unroll
    for (int p = 0; p < 4; p++) {
        const float* a = Ag + (size_t)(p * 32 + rr) * KXX + f * 8;
        ra[p][0] = *(const float4*)a;
        ra[p][1] = *(const float4*)(a + 4);
        rb[p] = *(const uint4*)(Bg + (size_t)(p * 32 + rr) * KXX + f * 8);
    }
    const int nst = kchunk >> 6;
    for (int kt = 0; kt < nst; kt++) {
        if (kt) __syncthreads();
        #pragma unroll
        for (int p = 0; p < 4; p++) {
            int row = p * 32 + rr;
            int slot = f ^ (row & 7);
            float4 v0 = ra[p][0], v1 = ra[p][1];
            uint4 o;
            o.x = f2bf(v0.x) | (f2bf(v0.y) << 16);
            o.y = f2bf(v0.z) | (f2bf(v0.w) << 16);
            o.z = f2bf(v1.x) | (f2bf(v1.y) << 16);
            o.w = f2bf(v1.z) | (f2bf(v1.w) << 16);
            *(uint4*)(Al + row * 64 + slot * 8) = o;
            *(uint4*)(Bl + row * 64 + slot * 8) = rb[p];
        }
        __syncthreads();
        if (kt + 1 < nst) {
            int kb = (kt + 1) * 64;
            #pragma unroll
            for (int p = 0; p < 4; p++) {
                const float* a = Ag + (size_t)(p * 32 + rr) * KXX + kb + f * 8;
                ra[p][0] = *(const float4*)a;
                ra[p][1] = *(const float4*)(a + 4);
                rb[p] = *(const uint4*)(Bg + (size_t)(p * 32 + rr) * KXX + kb + f * 8);
            }
        }
        #pragma unroll
        for (int s = 0; s < 2; s++) {
            bf8 af[4], bq[4];
            #pragma unroll
            for (int ff = 0; ff < 4; ff++) {
                int rowa = wm * 64 + ff * 16 + (lane & 15);
                int sla = (s * 4 + (lane >> 4)) ^ (rowa & 7);
                af[ff] = *reinterpret_cast<const bf8*>(Al + rowa * 64 + sla * 8);
                int rowb = wn * 64 + ff * 16 + (lane & 15);
                int slb = (s * 4 + (lane >> 4)) ^ (rowb & 7);
                bq[ff] = *reinterpret_cast<const bf8*>(Bl + rowb * 64 + slb * 8);
            }
            #pragma unroll
            for (int i = 0; i < 4; i++)
                #pragma unroll
                for (int j = 0; j < 4; j++)
                    acc[i][j] = __builtin_amdgcn_mfma_f32_16x16x32_bf16(af[i], bq[j], acc[i][j], 0, 0, 0);
        }
    }
    float* dst = Pm + (size_t)blockIdx.y * PM_SLICE;
    #pragma unroll
    for (int i = 0; i < 4; i++) {
        int row = m0 + wm * 64 + i * 16 + (lane >> 4) * 4;
        #pragma unroll
        for (int j = 0; j < 4; j++) {
            int col = wn * 64 + j * 16 + (lane & 15);
            #pragma unroll
            for (int q = 0; q < 4; q++)
                dst[(size_t)(row + q) * 128 + col] = acc[i][j][q];
        }
    }
}

__global__ __launch_bounds__(256) void k_mainred(const float* __restrict__ Pm,
                                                 const float* __restrict__ constv,
                                                 float* __restrict__ out, int nksm) {
    int tid = blockIdx.x * 256 + threadIdx.x;   // 2048*120
    int b = tid / NR, r = tid - b * NR;
    float s = constv[r];
    for (int ks = 0; ks < nksm; ks++)
        s += Pm[(size_t)ks * PM_SLICE + (size_t)b * 128 + r];
    out[tid] = s;
}

extern "C" void kernel_launch(void* const* d_in, const int* in_sizes, int n_in,
                              void* d_out, int out_size, void* d_ws, size_t ws_size,
                              hipStream_t stream) {
    const float* embeds = (const float*)d_in[0];
    const float* pw_w   = (const float*)d_in[1];
    const float* pw_b   = (const float*)d_in[2];
    const float* cls_w  = (const float*)d_in[3];
    const float* cls_b  = (const float*)d_in[4];
    float* out = (float*)d_out;

    unsigned short* C2R   = (unsigned short*)d_ws;          // 640*2048 bf16
    unsigned short* Afold = C2R + (size_t)640 * 2048;       // 1024*2048 bf16
    unsigned short* WTt   = Afold + (size_t)1024 * 2048;    // 128*5120 bf16
    float* constv = (float*)(WTt + (size_t)128 * 5120);     // 128 f32
    float* Pm = constv + 128;

    size_t base = ((size_t)640 * 2048 + (size_t)1024 * 2048 + (size_t)128 * 5120) * 2 + 512;
    size_t avail = (ws_size > base) ? (ws_size - base) / 4 : 0;
    const int cand[6] = {20, 16, 8, 4, 2, 1};
    int nksm = 1;
    for (int ci = 0; ci < 6; ci++) {
        if ((size_t)cand[ci] * PM_SLICE <= avail) { nksm = cand[ci]; break; }
    }
    int kchunk = KXX / nksm;

    k_prep<<<dim3(640, 2), dim3(256), 0, stream>>>(cls_w, C2R);
    k_wprep<<<dim3(16, 32), dim3(256), 0, stream>>>(pw_w, Afold);
    k_const<<<dim3(NR), dim3(256), 0, stream>>>(C2R, pw_b, cls_b, constv);
    k_fold<<<dim3(8, 5), dim3(256), 0, stream>>>(Afold, C2R, WTt);
    k_main<<<dim3(16, nksm), dim3(256), 0, stream>>>(embeds, WTt, Pm, kchunk);
    k_mainred<<<dim3(960), dim3(256), 0, stream>>>(Pm, constv, out, nksm);
}

// Round 6
// 201.488 us; speedup vs baseline: 1.3002x; 1.3002x over previous
//
#include <hip/hip_runtime.h>

// LocalSorterModel, collapsed + bf16 MFMA (16x16x32):
//   out[b,r] = sum_x E[b,x] * W[x,r] + const[r],  x = n*1024+d, K=5120
//   WTt[r][x] bf16 built by fold GEMM (K-split fp32 partials + reduce) from
//   Afold[d][k2] (pw_w repack) and C2R[n*128+r][k2] (cls_w pair-fold).
//   All operands K-contiguous bf16; staging lanes-along-K -> XOR-swizzled LDS.

#define NR 120
#define KXX 5120
#define PM_SLICE (2048*128)      // floats per main k-split slice
#define PF_SLICE (128*5120)      // floats per fold k-split slice (r-major, transposed)

typedef __attribute__((ext_vector_type(8))) short bf8;
typedef __attribute__((ext_vector_type(4))) float f4;

__device__ __forceinline__ unsigned int f2bf(float f) {
    unsigned int x = __builtin_bit_cast(unsigned int, f);
    return (x + 0x7fffu + ((x >> 16) & 1u)) >> 16;
}
__device__ __forceinline__ float bf2f(unsigned short u) {
    unsigned int x = ((unsigned int)u) << 16;
    return __builtin_bit_cast(float, x);
}

// ---- C2R: [640 col][2048 k2] bf16, col = n*128+r (r>=120 zero) ----
__global__ __launch_bounds__(256) void k_prep(const float* __restrict__ cls_w,
                                              unsigned short* __restrict__ C2R) {
    const int col = blockIdx.x, half = blockIdx.y, t = threadIdx.x;
    const int n = col >> 7, r = col & 127;
    unsigned short* dst = C2R + (size_t)col * 2048 + half * 1024 + t * 4;
    if (r >= NR) { *(unsigned long long*)dst = 0ull; return; }
    const float* base = cls_w + (size_t)r * 20480 + t * 4;
    float sx = 0, sy = 0, sz = 0, sw = 0;
    if (half == 0) {
        #pragma unroll
        for (int q = 0; q < 4; q++) {
            float4 v = *(const float4*)(base + (4 * n + q) * 1024);
            sx += v.x; sy += v.y; sz += v.z; sw += v.w;
        }
    } else {
        #pragma unroll
        for (int i = 0; i < 5; i++) {
            if (i == n) continue;
            int q = (n > i) ? (n - 1) : n;
            float4 v = *(const float4*)(base + (4 * i + q) * 1024);
            sx += v.x; sy += v.y; sz += v.z; sw += v.w;
        }
    }
    unsigned long long pk = (unsigned long long)f2bf(sx)
                          | ((unsigned long long)f2bf(sy) << 16)
                          | ((unsigned long long)f2bf(sz) << 32)
                          | ((unsigned long long)f2bf(sw) << 48);
    *(unsigned long long*)dst = pk;
}

// ---- Afold: [1024 d][2048 k2] bf16 = transposed/interleaved pw_w ----
__global__ __launch_bounds__(256) void k_wprep(const float* __restrict__ pw_w,
                                               unsigned short* __restrict__ Afold) {
    __shared__ float T[64][65];
    const int d0 = blockIdx.x * 64, kt0 = blockIdx.y * 64;
    const int h = blockIdx.y >> 4, kr0 = (blockIdx.y & 15) * 64;
    const int t = threadIdx.x;
    #pragma unroll
    for (int lp = 0; lp < 4; lp++) {
        int lk = lp * 16 + (t >> 4);
        float4 v = *(const float4*)(pw_w + (size_t)(kr0 + lk) * 2048 + h * 1024 + d0 + (t & 15) * 4);
        T[lk][(t & 15) * 4 + 0] = v.x; T[lk][(t & 15) * 4 + 1] = v.y;
        T[lk][(t & 15) * 4 + 2] = v.z; T[lk][(t & 15) * 4 + 3] = v.w;
    }
    __syncthreads();
    #pragma unroll
    for (int wp = 0; wp < 2; wp++) {
        int ld = wp * 32 + (t >> 3);
        int lk2 = (t & 7) * 8;
        uint4 o;
        o.x = f2bf(T[lk2 + 0][ld]) | (f2bf(T[lk2 + 1][ld]) << 16);
        o.y = f2bf(T[lk2 + 2][ld]) | (f2bf(T[lk2 + 3][ld]) << 16);
        o.z = f2bf(T[lk2 + 4][ld]) | (f2bf(T[lk2 + 5][ld]) << 16);
        o.w = f2bf(T[lk2 + 6][ld]) | (f2bf(T[lk2 + 7][ld]) << 16);
        *(uint4*)(Afold + (size_t)(d0 + ld) * 2048 + kt0 + lk2) = o;
    }
}

__global__ __launch_bounds__(256) void k_const(const unsigned short* __restrict__ C2R,
                                               const float* __restrict__ pw_b,
                                               const float* __restrict__ cls_b,
                                               float* __restrict__ constv) {
    const int r = blockIdx.x, t = threadIdx.x;
    float acc = 0.f;
    for (int k = t; k < 1024; k += 256) {
        float s = 0.f;
        #pragma unroll
        for (int n = 0; n < 5; n++) s += bf2f(C2R[(size_t)(n * 128 + r) * 2048 + k]);
        acc += s * pw_b[k];
    }
    __shared__ float red[256];
    red[t] = acc; __syncthreads();
    for (int s2 = 128; s2 > 0; s2 >>= 1) {
        if (t < s2) red[t] += red[t + s2];
        __syncthreads();
    }
    if (t == 0) constv[r] = cls_b[r] + red[0];
}

// ---- fold GEMM (MFMA): grid(8 d, 5 n, ksf), fp32 partials Pf[ks][128 r][5120 x] ----
__global__ __launch_bounds__(256) void k_fold(const unsigned short* __restrict__ Afold,
                                              const unsigned short* __restrict__ C2R,
                                              float* __restrict__ Pf, int kchunk) {
    __shared__ __align__(16) unsigned char smem[65536];
    unsigned short* Al = (unsigned short*)smem;
    unsigned short* Bl = Al + 128 * 64;
    const int d0 = blockIdx.x * 128, n = blockIdx.y;
    const int kc0 = blockIdx.z * kchunk;
    const int t = threadIdx.x, lane = t & 63, wv = t >> 6;
    const int wm = wv >> 1, wn = wv & 1;
    const int rr = t >> 3, f = t & 7;

    f4 acc[4][4];
    #pragma unroll
    for (int i = 0; i < 4; i++)
        #pragma unroll
        for (int j = 0; j < 4; j++) acc[i][j] = (f4){0.f, 0.f, 0.f, 0.f};

    const unsigned short* Ag = Afold + (size_t)d0 * 2048 + kc0;
    const unsigned short* Bg = C2R + (size_t)(n * 128) * 2048 + kc0;
    uint4 ra[4], rb[4];
    #pragma unroll
    for (int p = 0; p < 4; p++) {
        ra[p] = *(const uint4*)(Ag + (size_t)(p * 32 + rr) * 2048 + f * 8);
        rb[p] = *(const uint4*)(Bg + (size_t)(p * 32 + rr) * 2048 + f * 8);
    }
    const int nst = kchunk >> 6;
    for (int kt = 0; kt < nst; kt++) {
        if (kt) __syncthreads();
        #pragma unroll
        for (int p = 0; p < 4; p++) {
            int row = p * 32 + rr;
            int slot = f ^ (row & 7);
            *(uint4*)(Al + row * 64 + slot * 8) = ra[p];
            *(uint4*)(Bl + row * 64 + slot * 8) = rb[p];
        }
        __syncthreads();
        if (kt + 1 < nst) {
            int kb = (kt + 1) * 64;
            #pragma unroll
            for (int p = 0; p < 4; p++) {
                ra[p] = *(const uint4*)(Ag + (size_t)(p * 32 + rr) * 2048 + kb + f * 8);
                rb[p] = *(const uint4*)(Bg + (size_t)(p * 32 + rr) * 2048 + kb + f * 8);
            }
        }
        #pragma unroll
        for (int s = 0; s < 2; s++) {
            bf8 af[4], bq[4];
            #pragma unroll
            for (int ff = 0; ff < 4; ff++) {
                int rowa = wm * 64 + ff * 16 + (lane & 15);
                int sla = (s * 4 + (lane >> 4)) ^ (rowa & 7);
                af[ff] = *reinterpret_cast<const bf8*>(Al + rowa * 64 + sla * 8);
                int rowb = wn * 64 + ff * 16 + (lane & 15);
                int slb = (s * 4 + (lane >> 4)) ^ (rowb & 7);
                bq[ff] = *reinterpret_cast<const bf8*>(Bl + rowb * 64 + slb * 8);
            }
            #pragma unroll
            for (int i = 0; i < 4; i++)
                #pragma unroll
                for (int j = 0; j < 4; j++)
                    acc[i][j] = __builtin_amdgcn_mfma_f32_16x16x32_bf16(af[i], bq[j], acc[i][j], 0, 0, 0);
        }
    }
    // fp32 repack: T[128 r][128 d] (XOR-swizzled 16B slots), then coalesced Pf store
    __syncthreads();
    float* T = (float*)smem;
    #pragma unroll
    for (int i = 0; i < 4; i++) {
        int slog = wm * 16 + i * 4 + (lane >> 4);      // 16B slot in d
        #pragma unroll
        for (int j = 0; j < 4; j++) {
            int c = wn * 64 + j * 16 + (lane & 15);    // r row
            int sphy = slog ^ ((c & 7) << 2);
            *(f4*)(T + (size_t)c * 128 + sphy * 4) = acc[i][j];
        }
    }
    __syncthreads();
    float* dst = Pf + (size_t)blockIdx.z * PF_SLICE + n * 1024 + d0;
    #pragma unroll
    for (int pass = 0; pass < 4; pass++) {
        int c = pass * 32 + (t >> 3);
        #pragma unroll
        for (int u = 0; u < 4; u++) {
            int slog = (t & 7) + u * 8;
            int sphy = slog ^ ((c & 7) << 2);
            float4 v = *(const float4*)(T + (size_t)c * 128 + sphy * 4);
            *(float4*)(dst + (size_t)c * KXX + slog * 4) = v;
        }
    }
}

// ---- fold reduce: WTt[r][x] bf16 = sum_ks Pf[ks][r][x] ----
__global__ __launch_bounds__(256) void k_foldred(const float* __restrict__ Pf,
                                                 unsigned short* __restrict__ WTt,
                                                 int ksf) {
    int i4 = blockIdx.x * 256 + threadIdx.x;       // 163840 float4s
    const float4* p = (const float4*)Pf;
    float4 s = p[i4];
    for (int ks = 1; ks < ksf; ks++) {
        float4 v = p[(size_t)ks * (PF_SLICE / 4) + i4];
        s.x += v.x; s.y += v.y; s.z += v.z; s.w += v.w;
    }
    unsigned long long pk = (unsigned long long)f2bf(s.x)
                          | ((unsigned long long)f2bf(s.y) << 16)
                          | ((unsigned long long)f2bf(s.z) << 32)
                          | ((unsigned long long)f2bf(s.w) << 48);
    *(unsigned long long*)(WTt + (size_t)i4 * 4) = pk;
}

// ---- main GEMM (MFMA): A=E fp32 (cvt in staging), B=WTt bf16; 2-deep prefetch ----
__global__ __launch_bounds__(256) void k_main(const float* __restrict__ E,
                                              const unsigned short* __restrict__ WTt,
                                              float* __restrict__ Pm, int kchunk) {
    __shared__ __align__(16) unsigned short lds[2 * 128 * 64];
    unsigned short* Al = lds;
    unsigned short* Bl = lds + 128 * 64;
    const int m0 = blockIdx.x * 128;
    const int kc0 = blockIdx.y * kchunk;
    const int t = threadIdx.x, lane = t & 63, wv = t >> 6;
    const int wm = wv >> 1, wn = wv & 1;
    const int rr = t >> 3, f = t & 7;

    f4 acc[4][4];
    #pragma unroll
    for (int i = 0; i < 4; i++)
        #pragma unroll
        for (int j = 0; j < 4; j++) acc[i][j] = (f4){0.f, 0.f, 0.f, 0.f};

    const float* Ag = E + (size_t)m0 * KXX + kc0;
    const unsigned short* Bg = WTt + kc0;
    float4 raA[2][4][2];
    uint4 raB[2][4];
    const int nst = kchunk >> 6;
    #pragma unroll
    for (int st = 0; st < 2; st++) {
        int kb = st * 64;
        #pragma unroll
        for (int p = 0; p < 4; p++) {
            const float* a = Ag + (size_t)(p * 32 + rr) * KXX + kb + f * 8;
            raA[st][p][0] = *(const float4*)a;
            raA[st][p][1] = *(const float4*)(a + 4);
            raB[st][p] = *(const uint4*)(Bg + (size_t)(p * 32 + rr) * KXX + kb + f * 8);
        }
    }
    for (int kt = 0; kt < nst; kt++) {
        const int par = kt & 1;
        if (kt) __syncthreads();
        #pragma unroll
        for (int p = 0; p < 4; p++) {
            int row = p * 32 + rr;
            int slot = f ^ (row & 7);
            float4 v0 = raA[par][p][0], v1 = raA[par][p][1];
            uint4 o;
            o.x = f2bf(v0.x) | (f2bf(v0.y) << 16);
            o.y = f2bf(v0.z) | (f2bf(v0.w) << 16);
            o.z = f2bf(v1.x) | (f2bf(v1.y) << 16);
            o.w = f2bf(v1.z) | (f2bf(v1.w) << 16);
            *(uint4*)(Al + row * 64 + slot * 8) = o;
            *(uint4*)(Bl + row * 64 + slot * 8) = raB[par][p];
        }
        __syncthreads();
        if (kt + 2 < nst) {
            int kb = (kt + 2) * 64;
            #pragma unroll
            for (int p = 0; p < 4; p++) {
                const float* a = Ag + (size_t)(p * 32 + rr) * KXX + kb + f * 8;
                raA[par][p][0] = *(const float4*)a;
                raA[par][p][1] = *(const float4*)(a + 4);
                raB[par][p] = *(const uint4*)(Bg + (size_t)(p * 32 + rr) * KXX + kb + f * 8);
            }
        }
        #pragma unroll
        for (int s = 0; s < 2; s++) {
            bf8 af[4], bq[4];
            #pragma unroll
            for (int ff = 0; ff < 4; ff++) {
                int rowa = wm * 64 + ff * 16 + (lane & 15);
                int sla = (s * 4 + (lane >> 4)) ^ (rowa & 7);
                af[ff] = *reinterpret_cast<const bf8*>(Al + rowa * 64 + sla * 8);
                int rowb = wn * 64 + ff * 16 + (lane & 15);
                int slb = (s * 4 + (lane >> 4)) ^ (rowb & 7);
                bq[ff] = *reinterpret_cast<const bf8*>(Bl + rowb * 64 + slb * 8);
            }
            #pragma unroll
            for (int i = 0; i < 4; i++)
                #pragma unroll
                for (int j = 0; j < 4; j++)
                    acc[i][j] = __builtin_amdgcn_mfma_f32_16x16x32_bf16(af[i], bq[j], acc[i][j], 0, 0, 0);
        }
    }
    float* dst = Pm + (size_t)blockIdx.y * PM_SLICE;
    #pragma unroll
    for (int i = 0; i < 4; i++) {
        int row = m0 + wm * 64 + i * 16 + (lane >> 4) * 4;
        #pragma unroll
        for (int j = 0; j < 4; j++) {
            int col = wn * 64 + j * 16 + (lane & 15);
            #pragma unroll
            for (int q = 0; q < 4; q++)
                dst[(size_t)(row + q) * 128 + col] = acc[i][j][q];
        }
    }
}

__global__ __launch_bounds__(256) void k_mainred(const float* __restrict__ Pm,
                                                 const float* __restrict__ constv,
                                                 float* __restrict__ out, int nksm) {
    int tid = blockIdx.x * 256 + threadIdx.x;   // 2048*120
    int b = tid / NR, r = tid - b * NR;
    float s = constv[r];
    for (int ks = 0; ks < nksm; ks++)
        s += Pm[(size_t)ks * PM_SLICE + (size_t)b * 128 + r];
    out[tid] = s;
}

extern "C" void kernel_launch(void* const* d_in, const int* in_sizes, int n_in,
                              void* d_out, int out_size, void* d_ws, size_t ws_size,
                              hipStream_t stream) {
    const float* embeds = (const float*)d_in[0];
    const float* pw_w   = (const float*)d_in[1];
    const float* pw_b   = (const float*)d_in[2];
    const float* cls_w  = (const float*)d_in[3];
    const float* cls_b  = (const float*)d_in[4];
    float* out = (float*)d_out;

    unsigned short* C2R   = (unsigned short*)d_ws;          // 640*2048 bf16
    unsigned short* Afold = C2R + (size_t)640 * 2048;       // 1024*2048 bf16
    unsigned short* WTt   = Afold + (size_t)1024 * 2048;    // 128*5120 bf16
    float* constv = (float*)(WTt + (size_t)128 * 5120);     // 128 f32
    float* scratch = constv + 128;                          // Pf, then Pm (aliased)

    size_t base = ((size_t)640 * 2048 + (size_t)1024 * 2048 + (size_t)128 * 5120) * 2 + 512;
    size_t avail = (ws_size > base) ? (ws_size - base) / 4 : 0;
    const int candm[6] = {20, 16, 8, 4, 2, 1};
    int nksm = 1;
    for (int ci = 0; ci < 6; ci++)
        if ((size_t)candm[ci] * PM_SLICE <= avail) { nksm = candm[ci]; break; }
    const int candf[4] = {8, 4, 2, 1};
    int ksf = 1;
    for (int ci = 0; ci < 4; ci++)
        if ((size_t)candf[ci] * PF_SLICE <= avail) { ksf = candf[ci]; break; }

    k_prep<<<dim3(640, 2), dim3(256), 0, stream>>>(cls_w, C2R);
    k_wprep<<<dim3(16, 32), dim3(256), 0, stream>>>(pw_w, Afold);
    k_const<<<dim3(NR), dim3(256), 0, stream>>>(C2R, pw_b, cls_b, constv);
    k_fold<<<dim3(8, 5, ksf), dim3(256), 0, stream>>>(Afold, C2R, scratch, 2048 / ksf);
    k_foldred<<<dim3(640), dim3(256), 0, stream>>>(scratch, WTt, ksf);
    k_main<<<dim3(16, nksm), dim3(256), 0, stream>>>(embeds, WTt, scratch, KXX / nksm);
    k_mainred<<<dim3(960), dim3(256), 0, stream>>>(scratch, constv, out, nksm);
}

// Round 9
// 179.684 us; speedup vs baseline: 1.4580x; 1.1213x over previous
//
#include <hip/hip_runtime.h>

// LocalSorterModel, collapsed + bf16 MFMA (16x16x32):
//   out[b,r] = sum_x E[b,x] * W[x,r] + const[r],  x = n*1024+d, K=5120
//   WTt[r][x] bf16 built by fold GEMM (K-split fp32 partials + reduce) from
//   Afold[d][k2] (pw_w repack) and C2R[n*128+r][k2] (cls_w pair-fold).
//   64-row tiles, 2 blocks+/CU, coalesced epilogues via LDS repack.

#define NR 120
#define KXX 5120
#define PM_SLICE (2048*128)      // floats per main k-split slice  [b][r]
#define PF_SLICE (128*5120)      // floats per fold k-split slice  [r][x]

typedef __attribute__((ext_vector_type(8))) short bf8;
typedef __attribute__((ext_vector_type(4))) float f4;

__device__ __forceinline__ unsigned int f2bf(float f) {
    unsigned int x = __builtin_bit_cast(unsigned int, f);
    return (x + 0x7fffu + ((x >> 16) & 1u)) >> 16;
}
__device__ __forceinline__ float bf2f(unsigned short u) {
    unsigned int x = ((unsigned int)u) << 16;
    return __builtin_bit_cast(float, x);
}

// ---- C2R: [640 col][2048 k2] bf16, col = n*128+r (r>=120 zero) ----
__global__ __launch_bounds__(256) void k_prep(const float* __restrict__ cls_w,
                                              unsigned short* __restrict__ C2R) {
    const int col = blockIdx.x, half = blockIdx.y, t = threadIdx.x;
    const int n = col >> 7, r = col & 127;
    unsigned short* dst = C2R + (size_t)col * 2048 + half * 1024 + t * 4;
    if (r >= NR) { *(unsigned long long*)dst = 0ull; return; }
    const float* base = cls_w + (size_t)r * 20480 + t * 4;
    float sx = 0, sy = 0, sz = 0, sw = 0;
    if (half == 0) {
        #pragma unroll
        for (int q = 0; q < 4; q++) {
            float4 v = *(const float4*)(base + (4 * n + q) * 1024);
            sx += v.x; sy += v.y; sz += v.z; sw += v.w;
        }
    } else {
        #pragma unroll
        for (int i = 0; i < 5; i++) {
            if (i == n) continue;
            int q = (n > i) ? (n - 1) : n;
            float4 v = *(const float4*)(base + (4 * i + q) * 1024);
            sx += v.x; sy += v.y; sz += v.z; sw += v.w;
        }
    }
    unsigned long long pk = (unsigned long long)f2bf(sx)
                          | ((unsigned long long)f2bf(sy) << 16)
                          | ((unsigned long long)f2bf(sz) << 32)
                          | ((unsigned long long)f2bf(sw) << 48);
    *(unsigned long long*)dst = pk;
}

// ---- Afold: [1024 d][2048 k2] bf16 = transposed/interleaved pw_w ----
__global__ __launch_bounds__(256) void k_wprep(const float* __restrict__ pw_w,
                                               unsigned short* __restrict__ Afold) {
    __shared__ float T[64][65];
    const int d0 = blockIdx.x * 64, kt0 = blockIdx.y * 64;
    const int h = blockIdx.y >> 4, kr0 = (blockIdx.y & 15) * 64;
    const int t = threadIdx.x;
    #pragma unroll
    for (int lp = 0; lp < 4; lp++) {
        int lk = lp * 16 + (t >> 4);
        float4 v = *(const float4*)(pw_w + (size_t)(kr0 + lk) * 2048 + h * 1024 + d0 + (t & 15) * 4);
        T[lk][(t & 15) * 4 + 0] = v.x; T[lk][(t & 15) * 4 + 1] = v.y;
        T[lk][(t & 15) * 4 + 2] = v.z; T[lk][(t & 15) * 4 + 3] = v.w;
    }
    __syncthreads();
    #pragma unroll
    for (int wp = 0; wp < 2; wp++) {
        int ld = wp * 32 + (t >> 3);
        int lk2 = (t & 7) * 8;
        uint4 o;
        o.x = f2bf(T[lk2 + 0][ld]) | (f2bf(T[lk2 + 1][ld]) << 16);
        o.y = f2bf(T[lk2 + 2][ld]) | (f2bf(T[lk2 + 3][ld]) << 16);
        o.z = f2bf(T[lk2 + 4][ld]) | (f2bf(T[lk2 + 5][ld]) << 16);
        o.w = f2bf(T[lk2 + 6][ld]) | (f2bf(T[lk2 + 7][ld]) << 16);
        *(uint4*)(Afold + (size_t)(d0 + ld) * 2048 + kt0 + lk2) = o;
    }
}

// ---- const[r] = cls_b[r] + sum_k pw_b[k] * sum_{p<20} cls_w[r][p*1024+k] ----
// reads cls_w directly (no C2R dependency; fp32-exact gather)
__global__ __launch_bounds__(256) void k_const(const float* __restrict__ cls_w,
                                               const float* __restrict__ pw_b,
                                               const float* __restrict__ cls_b,
                                               float* __restrict__ constv) {
    const int r = blockIdx.x, t = threadIdx.x;
    const float* base = cls_w + (size_t)r * 20480;
    float acc = 0.f;
    for (int k = t; k < 1024; k += 256) {
        float s = 0.f;
        #pragma unroll
        for (int p = 0; p < 20; p++) s += base[p * 1024 + k];
        acc += s * pw_b[k];
    }
    __shared__ float red[256];
    red[t] = acc; __syncthreads();
    for (int s2 = 128; s2 > 0; s2 >>= 1) {
        if (t < s2) red[t] += red[t + s2];
        __syncthreads();
    }
    if (t == 0) constv[r] = cls_b[r] + red[0];
}

// ---- fold GEMM (MFMA): grid(16 d64, 5 n, ksf), fp32 partials Pf[ks][128 r][5120 x] ----
__global__ __launch_bounds__(256) void k_fold(const unsigned short* __restrict__ Afold,
                                              const unsigned short* __restrict__ C2R,
                                              float* __restrict__ Pf, int kchunk) {
    __shared__ __align__(16) unsigned char smem[34048];
    unsigned short* Al = (unsigned short*)smem;           // 64 x 64 bf16
    unsigned short* Bl = (unsigned short*)(smem + 8192);  // 128 x 64 bf16
    const int d0 = blockIdx.x * 64, n = blockIdx.y;
    const int kc0 = blockIdx.z * kchunk;
    const int t = threadIdx.x, lane = t & 63, wv = t >> 6;
    const int wm = wv >> 1, wn = wv & 1;
    const int rr = t >> 3, f = t & 7;

    f4 acc[2][4];
    #pragma unroll
    for (int i = 0; i < 2; i++)
        #pragma unroll
        for (int j = 0; j < 4; j++) acc[i][j] = (f4){0.f, 0.f, 0.f, 0.f};

    const unsigned short* Ag = Afold + (size_t)d0 * 2048 + kc0;
    const unsigned short* Bg = C2R + (size_t)(n * 128) * 2048 + kc0;
    uint4 ra[2], rb[4];
    #pragma unroll
    for (int p = 0; p < 2; p++)
        ra[p] = *(const uint4*)(Ag + (size_t)(p * 32 + rr) * 2048 + f * 8);
    #pragma unroll
    for (int p = 0; p < 4; p++)
        rb[p] = *(const uint4*)(Bg + (size_t)(p * 32 + rr) * 2048 + f * 8);

    const int nst = kchunk >> 6;
    for (int kt = 0; kt < nst; kt++) {
        if (kt) __syncthreads();
        #pragma unroll
        for (int p = 0; p < 2; p++) {
            int row = p * 32 + rr;
            int slot = f ^ (row & 7);
            *(uint4*)(Al + row * 64 + slot * 8) = ra[p];
        }
        #pragma unroll
        for (int p = 0; p < 4; p++) {
            int row = p * 32 + rr;
            int slot = f ^ (row & 7);
            *(uint4*)(Bl + row * 64 + slot * 8) = rb[p];
        }
        __syncthreads();
        if (kt + 1 < nst) {
            int kb = (kt + 1) * 64;
            #pragma unroll
            for (int p = 0; p < 2; p++)
                ra[p] = *(const uint4*)(Ag + (size_t)(p * 32 + rr) * 2048 + kb + f * 8);
            #pragma unroll
            for (int p = 0; p < 4; p++)
                rb[p] = *(const uint4*)(Bg + (size_t)(p * 32 + rr) * 2048 + kb + f * 8);
        }
        #pragma unroll
        for (int s = 0; s < 2; s++) {
            bf8 af[2], bq[4];
            #pragma unroll
            for (int ff = 0; ff < 2; ff++) {
                int rowa = wm * 32 + ff * 16 + (lane & 15);
                int sla = (s * 4 + (lane >> 4)) ^ (rowa & 7);
                af[ff] = *reinterpret_cast<const bf8*>(Al + rowa * 64 + sla * 8);
            }
            #pragma unroll
            for (int ff = 0; ff < 4; ff++) {
                int rowb = wn * 64 + ff * 16 + (lane & 15);
                int slb = (s * 4 + (lane >> 4)) ^ (rowb & 7);
                bq[ff] = *reinterpret_cast<const bf8*>(Bl + rowb * 64 + slb * 8);
            }
            #pragma unroll
            for (int i = 0; i < 2; i++)
                #pragma unroll
                for (int j = 0; j < 4; j++)
                    acc[i][j] = __builtin_amdgcn_mfma_f32_16x16x32_bf16(af[i], bq[j], acc[i][j], 0, 0, 0);
        }
    }
    // repack to T[128 r][64 d] fp32, 16B-slot XOR swizzle, then coalesced store
    __syncthreads();
    float* T = (float*)smem;
    #pragma unroll
    for (int i = 0; i < 2; i++) {
        int s16 = wm * 8 + i * 4 + (lane >> 4);
        #pragma unroll
        for (int j = 0; j < 4; j++) {
            int c = wn * 64 + j * 16 + (lane & 15);
            int sphy = s16 ^ (c & 15);
            *(f4*)(T + (size_t)c * 64 + sphy * 4) = acc[i][j];
        }
    }
    __syncthreads();
    float* dst = Pf + (size_t)blockIdx.z * PF_SLICE + n * 1024 + d0;
    #pragma unroll
    for (int pass = 0; pass < 4; pass++) {
        int c = pass * 32 + (t >> 3);
        #pragma unroll
        for (int u = 0; u < 2; u++) {
            int slog = (t & 7) + u * 8;
            int sphy = slog ^ (c & 15);
            float4 v = *(const float4*)(T + (size_t)c * 64 + sphy * 4);
            *(float4*)(dst + (size_t)c * KXX + slog * 4) = v;
        }
    }
}

// ---- fold reduce: WTt[r][x] bf16 = sum_ks Pf[ks][r][x] ----
__global__ __launch_bounds__(256) void k_foldred(const float* __restrict__ Pf,
                                                 unsigned short* __restrict__ WTt,
                                                 int ksf) {
    int i4 = blockIdx.x * 256 + threadIdx.x;       // 163840 float4s
    const float4* p = (const float4*)Pf;
    float4 s = p[i4];
    for (int ks = 1; ks < ksf; ks++) {
        float4 v = p[(size_t)ks * (PF_SLICE / 4) + i4];
        s.x += v.x; s.y += v.y; s.z += v.z; s.w += v.w;
    }
    unsigned long long pk = (unsigned long long)f2bf(s.x)
                          | ((unsigned long long)f2bf(s.y) << 16)
                          | ((unsigned long long)f2bf(s.z) << 32)
                          | ((unsigned long long)f2bf(s.w) << 48);
    *(unsigned long long*)(WTt + (size_t)i4 * 4) = pk;
}

// ---- main GEMM (MFMA): 64b x 128r tiles, grid(32, nksm); Pm[ks][b][r] ----
__global__ __launch_bounds__(256) void k_main(const float* __restrict__ E,
                                              const unsigned short* __restrict__ WTt,
                                              float* __restrict__ Pm, int kchunk) {
    __shared__ __align__(16) unsigned char smem[34048];
    unsigned short* Al = (unsigned short*)smem;           // 64 x 64 bf16
    unsigned short* Bl = (unsigned short*)(smem + 8192);  // 128 x 64 bf16
    const int m0 = blockIdx.x * 64;
    const int kc0 = blockIdx.y * kchunk;
    const int t = threadIdx.x, lane = t & 63, wv = t >> 6;
    const int wm = wv >> 1, wn = wv & 1;
    const int rrb = t >> 3, f = t & 7;     // B staging
    const int rra = t >> 2, fa = t & 3;    // A staging

    f4 acc[2][4];
    #pragma unroll
    for (int i = 0; i < 2; i++)
        #pragma unroll
        for (int j = 0; j < 4; j++) acc[i][j] = (f4){0.f, 0.f, 0.f, 0.f};

    const float* Ag = E + (size_t)m0 * KXX + kc0;
    const unsigned short* Bg = WTt + kc0;
    float4 raA[2][4];
    uint4 raB[2][4];
    const int nst = kchunk >> 6;
    #pragma unroll
    for (int st = 0; st < 2; st++) {
        int kb = st * 64;
        #pragma unroll
        for (int u = 0; u < 4; u++)
            raA[st][u] = *(const float4*)(Ag + (size_t)rra * KXX + kb + fa * 16 + u * 4);
        #pragma unroll
        for (int p = 0; p < 4; p++)
            raB[st][p] = *(const uint4*)(Bg + (size_t)(p * 32 + rrb) * KXX + kb + f * 8);
    }
    for (int kt = 0; kt < nst; kt++) {
        const int par = kt & 1;
        if (kt) __syncthreads();
        #pragma unroll
        for (int u = 0; u < 2; u++) {
            float4 v0 = raA[par][2 * u], v1 = raA[par][2 * u + 1];
            uint4 o;
            o.x = f2bf(v0.x) | (f2bf(v0.y) << 16);
            o.y = f2bf(v0.z) | (f2bf(v0.w) << 16);
            o.z = f2bf(v1.x) | (f2bf(v1.y) << 16);
            o.w = f2bf(v1.z) | (f2bf(v1.w) << 16);
            int slot = (fa * 2 + u) ^ (rra & 7);
            *(uint4*)(Al + rra * 64 + slot * 8) = o;
        }
        #pragma unroll
        for (int p = 0; p < 4; p++) {
            int row = p * 32 + rrb;
            int slot = f ^ (row & 7);
            *(uint4*)(Bl + row * 64 + slot * 8) = raB[par][p];
        }
        __syncthreads();
        if (kt + 2 < nst) {
            int kb = (kt + 2) * 64;
            #pragma unroll
            for (int u = 0; u < 4; u++)
                raA[par][u] = *(const float4*)(Ag + (size_t)rra * KXX + kb + fa * 16 + u * 4);
            #pragma unroll
            for (int p = 0; p < 4; p++)
                raB[par][p] = *(const uint4*)(Bg + (size_t)(p * 32 + rrb) * KXX + kb + f * 8);
        }
        #pragma unroll
        for (int s = 0; s < 2; s++) {
            bf8 af[2], bq[4];
            #pragma unroll
            for (int ff = 0; ff < 2; ff++) {
                int rowa = wm * 32 + ff * 16 + (lane & 15);
                int sla = (s * 4 + (lane >> 4)) ^ (rowa & 7);
                af[ff] = *reinterpret_cast<const bf8*>(Al + rowa * 64 + sla * 8);
            }
            #pragma unroll
            for (int ff = 0; ff < 4; ff++) {
                int rowb = wn * 64 + ff * 16 + (lane & 15);
                int slb = (s * 4 + (lane >> 4)) ^ (rowb & 7);
                bq[ff] = *reinterpret_cast<const bf8*>(Bl + rowb * 64 + slb * 8);
            }
            #pragma unroll
            for (int i = 0; i < 2; i++)
                #pragma unroll
                for (int j = 0; j < 4; j++)
                    acc[i][j] = __builtin_amdgcn_mfma_f32_16x16x32_bf16(af[i], bq[j], acc[i][j], 0, 0, 0);
        }
    }
    // repack acc -> padded LDS [64][132] -> coalesced full-row stores
    __syncthreads();
    float* T2 = (float*)smem;
    #pragma unroll
    for (int i = 0; i < 2; i++) {
        int rowb = wm * 32 + i * 16 + (lane >> 4) * 4;
        #pragma unroll
        for (int j = 0; j < 4; j++) {
            int colr = wn * 64 + j * 16 + (lane & 15);
            #pragma unroll
            for (int q = 0; q < 4; q++)
                T2[(size_t)(rowb + q) * 132 + colr] = acc[i][j][q];
        }
    }
    __syncthreads();
    float* dst = Pm + (size_t)blockIdx.y * PM_SLICE + (size_t)m0 * 128;
    {
        int row = t >> 2;
        int cb = (t & 3) * 32;
        #pragma unroll
        for (int u = 0; u < 8; u++) {
            int c = cb + u * 4;
            *(float4*)(dst + (size_t)row * 128 + c) = *(const float4*)(T2 + (size_t)row * 132 + c);
        }
    }
}

__global__ __launch_bounds__(256) void k_mainred(const float* __restrict__ Pm,
                                                 const float* __restrict__ constv,
                                                 float* __restrict__ out, int nksm) {
    int tid = blockIdx.x * 256 + threadIdx.x;   // 2048*120
    int b = tid / NR, r = tid - b * NR;
    float s = constv[r];
    for (int ks = 0; ks < nksm; ks++)
        s += Pm[(size_t)ks * PM_SLICE + (size_t)b * 128 + r];
    out[tid] = s;
}

extern "C" void kernel_launch(void* const* d_in, const int* in_sizes, int n_in,
                              void* d_out, int out_size, void* d_ws, size_t ws_size,
                              hipStream_t stream) {
    const float* embeds = (const float*)d_in[0];
    const float* pw_w   = (const float*)d_in[1];
    const float* pw_b   = (const float*)d_in[2];
    const float* cls_w  = (const float*)d_in[3];
    const float* cls_b  = (const float*)d_in[4];
    float* out = (float*)d_out;

    unsigned short* C2R   = (unsigned short*)d_ws;          // 640*2048 bf16
    unsigned short* Afold = C2R + (size_t)640 * 2048;       // 1024*2048 bf16
    unsigned short* WTt   = Afold + (size_t)1024 * 2048;    // 128*5120 bf16
    float* constv = (float*)(WTt + (size_t)128 * 5120);     // 128 f32
    float* scratch = constv + 128;                          // Pf, then Pm (aliased)

    size_t base = ((size_t)640 * 2048 + (size_t)1024 * 2048 + (size_t)128 * 5120) * 2 + 512;
    size_t avail = (ws_size > base) ? (ws_size - base) / 4 : 0;
    const int candm[5] = {16, 8, 4, 2, 1};
    int nksm = 1;
    for (int ci = 0; ci < 5; ci++)
        if ((size_t)candm[ci] * PM_SLICE <= avail) { nksm = candm[ci]; break; }
    const int candf[4] = {8, 4, 2, 1};
    int ksf = 1;
    for (int ci = 0; ci < 4; ci++)
        if ((size_t)candf[ci] * PF_SLICE <= avail) { ksf = candf[ci]; break; }

    k_const<<<dim3(NR), dim3(256), 0, stream>>>(cls_w, pw_b, cls_b, constv);
    k_prep<<<dim3(640, 2), dim3(256), 0, stream>>>(cls_w, C2R);
    k_wprep<<<dim3(16, 32), dim3(256), 0, stream>>>(pw_w, Afold);
    k_fold<<<dim3(16, 5, ksf), dim3(256), 0, stream>>>(Afold, C2R, scratch, 2048 / ksf);
    k_foldred<<<dim3(640), dim3(256), 0, stream>>>(scratch, WTt, ksf);
    k_main<<<dim3(32, nksm), dim3(256), 0, stream>>>(embeds, WTt, scratch, KXX / nksm);
    k_mainred<<<dim3(960), dim3(256), 0, stream>>>(scratch, constv, out, nksm);
}